// Round 1
// baseline (144.377 us; speedup 1.0000x reference)
//
#include <hip/hip_runtime.h>

#define B_ROWS 131072
#define IN_DIM 310
#define D_OUT  100
#define SLOPE  0.01f

__device__ __forceinline__ float leaky(float v) {
    return v >= 0.f ? v : SLOPE * v;
}

__global__ __launch_bounds__(256) void gen_mlp_kernel(
    const float* __restrict__ x, const float* __restrict__ data_t,
    const float* __restrict__ W1, const float* __restrict__ b1,
    const float* __restrict__ W2, const float* __restrict__ b2,
    const float* __restrict__ W3, const float* __restrict__ b3,
    float* __restrict__ out)
{
    // W1 transposed [10][384]: row padded past 310 with zeros so the
    // lane<27 tail (k in [256,310)) can read w without masking (0*0 = 0).
    __shared__ float sW1[10][384];
    __shared__ float sW2[10][128];
    __shared__ float sW3[2][128];   // transposed: sW3[c][j] = W3[j*2+c]
    __shared__ float sB1[10];
    __shared__ float sB2[128];
    __shared__ float sB3[2];

    const int t = threadIdx.x;

    // ---- one-time LDS staging (each location written exactly once) ----
    for (int i = t; i < 10 * 384; i += 256) {
        int j = i / 384, k = i - j * 384;
        sW1[j][k] = (k < IN_DIM) ? W1[k * 10 + j] : 0.f;
    }
    for (int i = t; i < 10 * 128; i += 256) ((float*)sW2)[i] = W2[i];
    { int j = t & 127, c = t >> 7; sW3[c][j] = W3[j * 2 + c]; } // 256 threads = 256 elems
    if (t < 10)  sB1[t] = b1[t];
    if (t < 128) sB2[t] = b2[t];
    if (t < 2)   sB3[t] = b3[t];
    __syncthreads();

    const int lane   = t & 63;
    const int wave   = blockIdx.x * (blockDim.x >> 6) + (t >> 6);
    const int nwaves = gridDim.x * (blockDim.x >> 6);

    for (int r = wave; r < B_ROWS; r += nwaves) {
        // ---- layer 1: x[310] . W1 -> h1[10], wave-cooperative ----
        // 310 floats = 155 float2; lanes cover 0..63, 64..127, 128..154
        const float2* xrow = (const float2*)(x + (size_t)r * IN_DIM);
        float2 xa = xrow[lane];
        float2 xb = xrow[lane + 64];
        float2 xc = (lane < 27) ? xrow[lane + 128] : make_float2(0.f, 0.f);

        float acc[10];
        #pragma unroll
        for (int j = 0; j < 10; ++j) {
            const float2* wr = (const float2*)&sW1[j][0];
            float2 wa = wr[lane];
            float2 wb = wr[lane + 64];
            float2 wc = wr[lane + 128];   // zero-padded region for lane>=27
            acc[j] = xa.x * wa.x + xa.y * wa.y
                   + xb.x * wb.x + xb.y * wb.y
                   + xc.x * wc.x + xc.y * wc.y;
        }
        // butterfly reduce+broadcast all 10 sums across the wave
        #pragma unroll
        for (int m = 1; m < 64; m <<= 1) {
            #pragma unroll
            for (int j = 0; j < 10; ++j)
                acc[j] += __shfl_xor(acc[j], m, 64);
        }
        float h1v[10];
        #pragma unroll
        for (int j = 0; j < 10; ++j) h1v[j] = leaky(acc[j] + sB1[j]);

        // ---- layer 2: h1[10] -> h2[128], lane j owns h2[j], h2[j+64] ----
        const int j1 = lane, j2 = lane + 64;
        float a1 = sB2[j1], a2 = sB2[j2];
        #pragma unroll
        for (int k = 0; k < 10; ++k) {
            a1 += h1v[k] * sW2[k][j1];
            a2 += h1v[k] * sW2[k][j2];
        }
        a1 = leaky(a1); a2 = leaky(a2);

        // ---- layer 3: h2[128] -> coeff[2] ----
        float p0 = a1 * sW3[0][j1] + a2 * sW3[0][j2];
        float p1 = a1 * sW3[1][j1] + a2 * sW3[1][j2];
        #pragma unroll
        for (int m = 1; m < 64; m <<= 1) {
            p0 += __shfl_xor(p0, m, 64);
            p1 += __shfl_xor(p1, m, 64);
        }
        const float c0 = leaky(p0 + sB3[0]);
        const float c1 = leaky(p1 + sB3[1]);

        // ---- output: out[d] = c0*t + c1*t^2 = t*(c0 + c1*t), D=100 ----
        const size_t base = (size_t)r * D_OUT;
        float tv = data_t[base + lane];
        out[base + lane] = tv * (c0 + c1 * tv);
        if (lane < D_OUT - 64) {
            float tw = data_t[base + 64 + lane];
            out[base + 64 + lane] = tw * (c0 + c1 * tw);
        }
    }
}

extern "C" void kernel_launch(void* const* d_in, const int* in_sizes, int n_in,
                              void* d_out, int out_size, void* d_ws, size_t ws_size,
                              hipStream_t stream) {
    const float* x      = (const float*)d_in[0];
    const float* data_t = (const float*)d_in[1];
    const float* W1     = (const float*)d_in[2];
    const float* b1     = (const float*)d_in[3];
    const float* W2     = (const float*)d_in[4];
    const float* b2     = (const float*)d_in[5];
    const float* W3     = (const float*)d_in[6];
    const float* b3     = (const float*)d_in[7];
    float* out = (float*)d_out;

    // 2048 blocks x 4 waves = 8192 waves; 131072 rows -> exactly 16 rows/wave
    gen_mlp_kernel<<<2048, 256, 0, stream>>>(x, data_t, W1, b1, W2, b2, W3, b3, out);
}